// Round 5
// baseline (686.633 us; speedup 1.0000x reference)
//
#include <hip/hip_runtime.h>

#define N_NODES 50000
#define N_EDGES 800000
#define N_GRAPHS 64
#define F 256        // F_IN == F_HID
#define F_OUT 128
#define G_DIM 768    // 3*F
#define SCAN_NB ((N_NODES + 255) / 256)   // 196
#define POOL_CHUNKS 16

typedef short short8 __attribute__((ext_vector_type(8)));
typedef short short4v __attribute__((ext_vector_type(4)));
typedef float float4v __attribute__((ext_vector_type(4)));

// ---- bf16 split helpers (RNE) ----
__device__ __forceinline__ unsigned short f2bf(float f) {
    unsigned int u = __float_as_uint(f);
    u += 0x7FFFu + ((u >> 16) & 1u);
    return (unsigned short)(u >> 16);
}
__device__ __forceinline__ float bf2f(unsigned short s) {
    return __uint_as_float(((unsigned int)s) << 16);
}

// ---- async global->LDS, 16B per lane; LDS dest = uniform base + lane*16 ----
__device__ __forceinline__ void gld_lds16(const void* gsrc, void* ldst) {
    __builtin_amdgcn_global_load_lds(
        (const __attribute__((address_space(1))) unsigned int*)gsrc,
        (__attribute__((address_space(3))) unsigned int*)ldst, 16, 0, 0);
}

// ---------------- degree count (int) ----------------
__global__ void count_deg(const int* __restrict__ dst, int* deg) {
    int e = blockIdx.x * blockDim.x + threadIdx.x;
    if (e < N_EDGES) atomicAdd(&deg[dst[e]], 1);
}

__global__ void compute_dinv(const int* __restrict__ deg, float* dinv) {
    int i = blockIdx.x * blockDim.x + threadIdx.x;
    if (i < N_NODES) dinv[i] = rsqrtf((float)(deg[i] + 1));   // +1 self-loop
}

// ---------------- 3-kernel exclusive scan over deg -> row_ptr ----------------
__global__ void scan_blocks(const int* __restrict__ deg, int* __restrict__ row_ptr,
                            int* __restrict__ block_tot) {
    __shared__ int sd[256];
    int t = threadIdx.x;
    int idx = blockIdx.x * 256 + t;
    int v = (idx < N_NODES) ? deg[idx] : 0;
    sd[t] = v;
    __syncthreads();
    for (int off = 1; off < 256; off <<= 1) {
        int a = (t >= off) ? sd[t - off] : 0;
        __syncthreads();
        sd[t] += a;
        __syncthreads();
    }
    if (idx < N_NODES) row_ptr[idx] = sd[t] - v;
    if (t == 255) block_tot[blockIdx.x] = sd[255];
}

__global__ void scan_totals(int* block_tot) {
    __shared__ int sd[256];
    int t = threadIdx.x;
    int v = (t < SCAN_NB) ? block_tot[t] : 0;
    sd[t] = v;
    __syncthreads();
    for (int off = 1; off < 256; off <<= 1) {
        int a = (t >= off) ? sd[t - off] : 0;
        __syncthreads();
        sd[t] += a;
        __syncthreads();
    }
    if (t < SCAN_NB) block_tot[t] = sd[t] - v;
}

__global__ void add_offsets(int* __restrict__ row_ptr, const int* __restrict__ block_tot) {
    int idx = blockIdx.x * 256 + threadIdx.x;
    if (idx < N_NODES) row_ptr[idx] += block_tot[blockIdx.x];
    if (idx == 0) row_ptr[N_NODES] = N_EDGES;
}

// ---------------- bucket edges into CSR order ----------------
__global__ void bucket_edges(const int* __restrict__ src, const int* __restrict__ dst,
                             const int* __restrict__ row_ptr, int* __restrict__ cursor,
                             int* __restrict__ srcs_sorted) {
    int e = blockIdx.x * blockDim.x + threadIdx.x;
    if (e < N_EDGES) {
        int d = dst[e];
        int pos = atomicAdd(&cursor[d], 1);
        srcs_sorted[row_ptr[d] + pos] = src[e];
    }
}

// ---------------- casts ----------------
__global__ void cast_split(const float* __restrict__ A, short* __restrict__ hi,
                           short* __restrict__ lo, int n4) {
    int i = blockIdx.x * blockDim.x + threadIdx.x;
    if (i < n4) {
        float4 v = ((const float4*)A)[i];
        short4v h, l;
        h.x = (short)f2bf(v.x); l.x = (short)f2bf(v.x - bf2f(h.x));
        h.y = (short)f2bf(v.y); l.y = (short)f2bf(v.y - bf2f(h.y));
        h.z = (short)f2bf(v.z); l.z = (short)f2bf(v.z - bf2f(h.z));
        h.w = (short)f2bf(v.w); l.w = (short)f2bf(v.w - bf2f(h.w));
        ((short4v*)hi)[i] = h;
        ((short4v*)lo)[i] = l;
    }
}

// W [256][256] -> transposed hi/lo: Bt[n][k] = W[k][n]
__global__ void cast_w_t(const float* __restrict__ W, short* __restrict__ hi,
                         short* __restrict__ lo) {
    int n = blockIdx.x;    // 256
    int k = threadIdx.x;   // 256
    float v = W[k * 256 + n];
    unsigned short h = f2bf(v);
    hi[n * 256 + k] = (short)h;
    lo[n * 256 + k] = (short)f2bf(v - bf2f(h));
}

// ---------------- split-bf16 MFMA GEMM with LDS staging ----------------
#define BM 128
#define BN 128
#define BK 32
__global__ __launch_bounds__(256) void gemm_mfma(
        const short* __restrict__ Ahi, const short* __restrict__ Alo,
        const short* __restrict__ Bthi, const short* __restrict__ Btlo,
        float* __restrict__ C, int M) {
    __shared__ short sAh[BM * BK], sAl[BM * BK], sBh[BN * BK], sBl[BN * BK];
    int tid = threadIdx.x;
    int wave = tid >> 6, lane = tid & 63;
    int q = lane >> 4, t = lane & 15;
    int row0 = blockIdx.y * BM;
    int col0 = blockIdx.x * BN;
    int wr = (wave >> 1) * 64;
    int wc = (wave & 1) * 64;

    int lrow = lane >> 2;          // 0..15
    int lk = (lane & 3) * 8;       // k offset (shorts)
    int srow0 = wave * 32;

    float4v acc[4][4] = {};
    for (int kt = 0; kt < 256; kt += BK) {
#pragma unroll
        for (int half = 0; half < 2; ++half) {
            int r = srow0 + half * 16 + lrow;
            int ga = row0 + r; if (ga >= M) ga = M - 1;   // clamp; never stored
            size_t aoff = (size_t)ga * 256 + kt + lk;
            size_t boff = (size_t)(col0 + r) * 256 + kt + lk;
            int ldso = (srow0 + half * 16) * BK;
            gld_lds16(&Ahi[aoff], &sAh[ldso]);
            gld_lds16(&Alo[aoff], &sAl[ldso]);
            gld_lds16(&Bthi[boff], &sBh[ldso]);
            gld_lds16(&Btlo[boff], &sBl[ldso]);
        }
        __syncthreads();
        short8 ah[4], al[4], bh[4], bl[4];
#pragma unroll
        for (int mi = 0; mi < 4; ++mi) {
            int r = wr + mi * 16 + t;
            ah[mi] = *(const short8*)&sAh[r * BK + q * 8];
            al[mi] = *(const short8*)&sAl[r * BK + q * 8];
        }
#pragma unroll
        for (int ni = 0; ni < 4; ++ni) {
            int n = wc + ni * 16 + t;
            bh[ni] = *(const short8*)&sBh[n * BK + q * 8];
            bl[ni] = *(const short8*)&sBl[n * BK + q * 8];
        }
#pragma unroll
        for (int mi = 0; mi < 4; ++mi)
#pragma unroll
            for (int ni = 0; ni < 4; ++ni) {
                acc[mi][ni] = __builtin_amdgcn_mfma_f32_16x16x32_bf16(ah[mi], bh[ni], acc[mi][ni], 0, 0, 0);
                acc[mi][ni] = __builtin_amdgcn_mfma_f32_16x16x32_bf16(ah[mi], bl[ni], acc[mi][ni], 0, 0, 0);
                acc[mi][ni] = __builtin_amdgcn_mfma_f32_16x16x32_bf16(al[mi], bh[ni], acc[mi][ni], 0, 0, 0);
            }
        __syncthreads();
    }
#pragma unroll
    for (int mi = 0; mi < 4; ++mi) {
        int gr0 = row0 + wr + mi * 16 + q * 4;
#pragma unroll
        for (int rr = 0; rr < 4; ++rr) {
            int gr = gr0 + rr;
            if (gr < M) {
#pragma unroll
                for (int ni = 0; ni < 4; ++ni)
                    C[(size_t)gr * 256 + col0 + wc + ni * 16 + t] = acc[mi][ni][rr];
            }
        }
    }
}

// -------- feature-sliced CSR gather-aggregate (XCD-affine), fused epilogue --------
// block b: chunk = b&7 (-> XCD b%8 under round-robin dispatch), node = b>>3.
// Each chunk covers 32 feats; per XCD the touched h-slice is 6.4 MB (L2-resident).
// Arithmetic identical to full-row version (same neighbor order per feature).
template<bool BF16OUT>
__global__ __launch_bounds__(64) void gather_agg_sliced(
        const int* __restrict__ row_ptr, const int* __restrict__ srcs,
        const float* __restrict__ dinv, const float* __restrict__ hW,
        const float* __restrict__ b, float* __restrict__ outF,
        short* __restrict__ outHi, short* __restrict__ outLo) {
    int blk = blockIdx.x;
    int chunk = blk & 7;
    int node = blk >> 3;
    int lane = threadIdx.x;                 // 64
    int f = chunk * 32 + (lane & 31);       // lanes 32-63 duplicate 0-31 (same line)
    int beg = row_ptr[node], end = row_ptr[node + 1];
    float dd = dinv[node];
    float acc = 0.f;
    for (int cbeg = beg; cbeg < end; cbeg += 64) {
        int n = end - cbeg; if (n > 64) n = 64;
        int sv = (lane < n) ? srcs[cbeg + lane] : 0;
        float wv = (lane < n) ? dinv[sv] * dd : 0.f;
        int i = 0;
        for (; i + 8 <= n; i += 8) {
            int s0 = __shfl(sv, i),     s1 = __shfl(sv, i + 1);
            int s2 = __shfl(sv, i + 2), s3 = __shfl(sv, i + 3);
            int s4 = __shfl(sv, i + 4), s5 = __shfl(sv, i + 5);
            int s6 = __shfl(sv, i + 6), s7 = __shfl(sv, i + 7);
            float v0 = hW[(size_t)s0 * 256 + f];
            float v1 = hW[(size_t)s1 * 256 + f];
            float v2 = hW[(size_t)s2 * 256 + f];
            float v3 = hW[(size_t)s3 * 256 + f];
            float v4 = hW[(size_t)s4 * 256 + f];
            float v5 = hW[(size_t)s5 * 256 + f];
            float v6 = hW[(size_t)s6 * 256 + f];
            float v7 = hW[(size_t)s7 * 256 + f];
            acc = fmaf(v0, __shfl(wv, i),     acc);
            acc = fmaf(v1, __shfl(wv, i + 1), acc);
            acc = fmaf(v2, __shfl(wv, i + 2), acc);
            acc = fmaf(v3, __shfl(wv, i + 3), acc);
            acc = fmaf(v4, __shfl(wv, i + 4), acc);
            acc = fmaf(v5, __shfl(wv, i + 5), acc);
            acc = fmaf(v6, __shfl(wv, i + 6), acc);
            acc = fmaf(v7, __shfl(wv, i + 7), acc);
        }
        for (; i < n; ++i) {
            int s = __shfl(sv, i);
            float w = __shfl(wv, i);
            acc = fmaf(hW[(size_t)s * 256 + f], w, acc);
        }
    }
    // self-loop + bias + relu
    float self = hW[(size_t)node * 256 + f];
    acc = fmaxf(fmaf(self, dd * dd, acc) + b[f], 0.f);
    if (lane < 32) {
        size_t o = (size_t)node * 256 + f;
        if (BF16OUT) {
            unsigned short h = f2bf(acc);
            outHi[o] = (short)h;
            outLo[o] = (short)f2bf(acc - bf2f(h));
        } else {
            outF[o] = acc;
        }
    }
}

// ---------------- parallel triple pooling (float4, 1 wave/block) ----------------
__global__ __launch_bounds__(64) void pool_partial(
        const float* __restrict__ h, const int* __restrict__ batch,
        float* __restrict__ psum, int* __restrict__ pmaxi) {
    int g = blockIdx.x;
    int chunk = blockIdx.y;
    int lane = threadIdx.x;  // 64; lane covers feats lane*4..lane*4+3
    int lo = 0, hi = N_NODES;
    while (lo < hi) { int mid = (lo + hi) >> 1; if (batch[mid] < g) lo = mid + 1; else hi = mid; }
    int start = lo;
    lo = 0; hi = N_NODES;
    while (lo < hi) { int mid = (lo + hi) >> 1; if (batch[mid] < g + 1) lo = mid + 1; else hi = mid; }
    int end = lo;
    int len = end - start;
    if (len <= 0) return;
    int per = (len + POOL_CHUNKS - 1) / POOL_CHUNKS;
    int cs = start + chunk * per;
    int ce = cs + per; if (ce > end) ce = end;
    if (cs >= ce) return;
    const float4* hv = (const float4*)h;
    float4 sum = make_float4(0.f, 0.f, 0.f, 0.f);
    float4 mx  = make_float4(0.f, 0.f, 0.f, 0.f);
    for (int n = cs; n < ce; ++n) {
        float4 v = hv[(size_t)n * 64 + lane];
        sum.x += v.x; sum.y += v.y; sum.z += v.z; sum.w += v.w;
        mx.x = fmaxf(mx.x, v.x); mx.y = fmaxf(mx.y, v.y);
        mx.z = fmaxf(mx.z, v.z); mx.w = fmaxf(mx.w, v.w);
    }
    float* ps = &psum[g * F + lane * 4];
    atomicAdd(&ps[0], sum.x); atomicAdd(&ps[1], sum.y);
    atomicAdd(&ps[2], sum.z); atomicAdd(&ps[3], sum.w);
    int* pm = &pmaxi[g * F + lane * 4];
    atomicMax(&pm[0], __float_as_int(mx.x)); atomicMax(&pm[1], __float_as_int(mx.y));
    atomicMax(&pm[2], __float_as_int(mx.z)); atomicMax(&pm[3], __float_as_int(mx.w));
}

// ---------------- final GEMM: out[64,128] = [mean|max|sum] @ Wfc + bfc ----------------
__global__ void final_gemm(const float* __restrict__ psum, const int* __restrict__ pmaxi,
                           const int* __restrict__ batch,
                           const float* __restrict__ Wfc, const float* __restrict__ bfc,
                           float* __restrict__ out) {
    int g = blockIdx.x;   // 64
    int o = threadIdx.x;  // 128
    __shared__ float row[G_DIM];
    __shared__ int s_cnt;
    if (threadIdx.x == 0) {
        int lo = 0, hi = N_NODES;
        while (lo < hi) { int mid = (lo + hi) >> 1; if (batch[mid] < g) lo = mid + 1; else hi = mid; }
        int start = lo;
        lo = 0; hi = N_NODES;
        while (lo < hi) { int mid = (lo + hi) >> 1; if (batch[mid] < g + 1) lo = mid + 1; else hi = mid; }
        s_cnt = lo - start;
    }
    __syncthreads();
    float inv = 1.0f / fmaxf((float)s_cnt, 1.0f);
    for (int i = threadIdx.x; i < F; i += 128) {
        float s = psum[g * F + i];
        row[i]       = s * inv;
        row[F + i]   = __int_as_float(pmaxi[g * F + i]);
        row[2*F + i] = s;
    }
    __syncthreads();
    float acc = bfc[o];
    for (int k = 0; k < G_DIM; ++k) acc += row[k] * Wfc[k * F_OUT + o];
    out[g * F_OUT + o] = acc;
}

extern "C" void kernel_launch(void* const* d_in, const int* in_sizes, int n_in,
                              void* d_out, int out_size, void* d_ws, size_t ws_size,
                              hipStream_t stream) {
    const float* x    = (const float*)d_in[0];
    const int*   ei   = (const int*)d_in[1];
    const int*   batch= (const int*)d_in[2];
    const float* W1   = (const float*)d_in[4];
    const float* b1   = (const float*)d_in[5];
    const float* W2   = (const float*)d_in[6];
    const float* b2   = (const float*)d_in[7];
    const float* Wfc  = (const float*)d_in[8];
    const float* bfc  = (const float*)d_in[9];
    float* out = (float*)d_out;

    const int* src = ei;
    const int* dst = ei + N_EDGES;

    const size_t NF = (size_t)N_NODES * F;   // 12.8M

    float* bufA  = (float*)d_ws;             // [N,256] fp32 gemm out (51.2 MB)
    short* xhi   = (short*)(bufA + NF);      // [N,256] bf16 hi — reused as h1hi
    short* xlo   = xhi + NF;                 // lo — reused as h1lo
    float* h2    = (float*)xhi;              // alias: layer-2 fp32 out spans xhi+xlo
    short* w1hi  = xlo + NF;
    short* w1lo  = w1hi + 65536;
    short* w2hi  = w1lo + 65536;
    short* w2lo  = w2hi + 65536;
    float* dinv  = (float*)(w2lo + 65536);
    int*   deg   = (int*)(dinv + N_NODES);
    int*   cursor= deg + N_NODES;
    int*   row_ptr = cursor + N_NODES;
    int*   btot  = row_ptr + N_NODES + 1;
    int*   srcs_s = btot + 256;
    float* psum  = (float*)(srcs_s + N_EDGES);   // [64][256]
    int*   pmaxi = (int*)(psum + N_GRAPHS * F);  // [64][256]

    // ---- degree + norm + CSR ----
    hipMemsetAsync(deg, 0, 2 * N_NODES * sizeof(int), stream);   // deg + cursor
    count_deg<<<(N_EDGES + 255) / 256, 256, 0, stream>>>(dst, deg);
    compute_dinv<<<(N_NODES + 255) / 256, 256, 0, stream>>>(deg, dinv);
    scan_blocks<<<SCAN_NB, 256, 0, stream>>>(deg, row_ptr, btot);
    scan_totals<<<1, 256, 0, stream>>>(btot);
    add_offsets<<<SCAN_NB, 256, 0, stream>>>(row_ptr, btot);
    bucket_edges<<<(N_EDGES + 255) / 256, 256, 0, stream>>>(src, dst, row_ptr, cursor, srcs_s);

    // ---- casts ----
    cast_split<<<(NF / 4 + 255) / 256, 256, 0, stream>>>(x, xhi, xlo, NF / 4);
    cast_w_t<<<256, 256, 0, stream>>>(W1, w1hi, w1lo);
    cast_w_t<<<256, 256, 0, stream>>>(W2, w2hi, w2lo);

    dim3 ggrid(2, (N_NODES + BM - 1) / BM);   // (2, 391)

    // ---- layer 1 ----
    gemm_mfma<<<ggrid, 256, 0, stream>>>(xhi, xlo, w1hi, w1lo, bufA, N_NODES);
    gather_agg_sliced<true><<<N_NODES * 8, 64, 0, stream>>>(row_ptr, srcs_s, dinv, bufA, b1,
                                                            nullptr, xhi, xlo);

    // ---- layer 2 ----
    gemm_mfma<<<ggrid, 256, 0, stream>>>(xhi, xlo, w2hi, w2lo, bufA, N_NODES);
    gather_agg_sliced<false><<<N_NODES * 8, 64, 0, stream>>>(row_ptr, srcs_s, dinv, bufA, b2,
                                                             h2, nullptr, nullptr);

    // ---- pooling + classifier ----
    hipMemsetAsync(psum, 0, N_GRAPHS * F * 2 * sizeof(float), stream);
    pool_partial<<<dim3(N_GRAPHS, POOL_CHUNKS), 64, 0, stream>>>(h2, batch, psum, pmaxi);
    final_gemm<<<N_GRAPHS, F_OUT, 0, stream>>>(psum, pmaxi, batch, Wfc, bfc, out);
}